// Round 2
// baseline (977.051 us; speedup 1.0000x reference)
//
#include <hip/hip_runtime.h>
#include <hip/hip_bf16.h>

// ROIPooler (FPN multi-level ROIAlign, aligned=true), float32 in/out, f32 compute.
// B=2, C=256, N=256 boxes/image -> R=512 ROIs. OUT=7, SR=2 -> 14x14 samples.
// Levels: idx 0..3 <-> feats 256^2/128^2/64^2/32^2, scales 1/4,1/8,1/16,1/32.

#define OUTD 7
#define SRD  2
#define SD   14     // OUTD*SRD
#define CCH  256
#define NBOX 256

__global__ __launch_bounds__(256) void roi_pool_kernel(
    const float* __restrict__ f0,
    const float* __restrict__ f1,
    const float* __restrict__ f2,
    const float* __restrict__ f3,
    const float* __restrict__ boxes,
    float* __restrict__ out)
{
    const int roi  = blockIdx.x;     // 0..R-1
    const int half = blockIdx.y;     // 0: bin rows 0-3, 1: rows 4-6
    const int c    = threadIdx.x;    // channel
    const int b    = roi / NBOX;

    const float bx1 = boxes[roi * 4 + 0];
    const float by1 = boxes[roi * 4 + 1];
    const float bx2 = boxes[roi * 4 + 2];
    const float by2 = boxes[roi * 4 + 3];

    // Level assignment (wave-uniform: all threads same roi).
    const float area = (bx2 - bx1) * (by2 - by1);
    const float sz   = sqrtf(area);
    int lvl = (int)floorf(4.0f + log2f(sz * (1.0f / 224.0f) + 1e-8f));
    lvl = min(max(lvl, 2), 5) - 2;   // 0..3

    const int   H     = 256 >> lvl;
    const int   W     = H;
    const float scale = 1.0f / (float)(4 << lvl);

    const float* f = (lvl == 0) ? f0 : (lvl == 1) ? f1 : (lvl == 2) ? f2 : f3;

    // Per-ROI sampling metadata, shared across channels.
    __shared__ int   s_y0[SD], s_y1[SD], s_x0[SD], s_x1[SD];
    __shared__ float s_ly[SD], s_lx[SD];
    __shared__ int   s_vy[SD], s_vx[SD];

    if (threadIdx.x < SD) {
        const int i = threadIdx.x;
        // Mirror reference op order: offset by -0.5 first, then bin size.
        const float x1r = bx1 * scale - 0.5f;
        const float y1r = by1 * scale - 0.5f;
        const float x2r = bx2 * scale - 0.5f;
        const float y2r = by2 * scale - 0.5f;
        const float bw = (x2r - x1r) * (1.0f / OUTD);
        const float bh = (y2r - y1r) * (1.0f / OUTD);
        const float g  = ((float)i + 0.5f) * (1.0f / SRD);
        const float ys = y1r + g * bh;
        const float xs = x1r + g * bw;
        s_vy[i] = (ys >= -1.0f) && (ys <= (float)H);
        s_vx[i] = (xs >= -1.0f) && (xs <= (float)W);
        const float yc = fminf(fmaxf(ys, 0.0f), (float)(H - 1));
        const float xc = fminf(fmaxf(xs, 0.0f), (float)(W - 1));
        const int y0 = (int)yc;   // yc >= 0, trunc == floor
        const int x0 = (int)xc;
        s_y0[i] = y0;
        s_x0[i] = x0;
        s_y1[i] = min(y0 + 1, H - 1);
        s_x1[i] = min(x0 + 1, W - 1);
        s_ly[i] = yc - (float)y0;
        s_lx[i] = xc - (float)x0;
    }
    __syncthreads();

    const size_t HW = (size_t)H * (size_t)W;
    const float* fb = f + (size_t)(b * CCH + c) * HW;
    float* orow = out + ((size_t)roi * CCH + c) * (OUTD * OUTD);

    const int oyb = half ? 4 : 0;
    const int oye = half ? 7 : 4;

    for (int oy = oyb; oy < oye; ++oy) {
        const int   ia   = oy * 2, ib = oy * 2 + 1;
        const int   vy_a = s_vy[ia], vy_b = s_vy[ib];
        const int   ya0  = s_y0[ia] * W, ya1 = s_y1[ia] * W;
        const int   yb0  = s_y0[ib] * W, yb1 = s_y1[ib] * W;
        const float lya  = s_ly[ia], hya = 1.0f - lya;
        const float lyb  = s_ly[ib], hyb = 1.0f - lyb;
        #pragma unroll
        for (int ox = 0; ox < OUTD; ++ox) {
            float acc = 0.0f;
            #pragma unroll
            for (int sx = 0; sx < SRD; ++sx) {
                const int j = ox * 2 + sx;
                if (!s_vx[j]) continue;            // wave-uniform
                const int   x0 = s_x0[j], x1 = s_x1[j];
                const float lx = s_lx[j], hx = 1.0f - lx;
                if (vy_a) {
                    const float va = fb[ya0 + x0];
                    const float vb = fb[ya0 + x1];
                    const float vc = fb[ya1 + x0];
                    const float vd = fb[ya1 + x1];
                    acc += hya * (hx * va + lx * vb) + lya * (hx * vc + lx * vd);
                }
                if (vy_b) {
                    const float va = fb[yb0 + x0];
                    const float vb = fb[yb0 + x1];
                    const float vc = fb[yb1 + x0];
                    const float vd = fb[yb1 + x1];
                    acc += hyb * (hx * va + lx * vb) + lyb * (hx * vc + lx * vd);
                }
            }
            orow[oy * OUTD + ox] = acc * 0.25f;
        }
    }
}

extern "C" void kernel_launch(void* const* d_in, const int* in_sizes, int n_in,
                              void* d_out, int out_size, void* d_ws, size_t ws_size,
                              hipStream_t stream) {
    const float* f0    = (const float*)d_in[0];
    const float* f1    = (const float*)d_in[1];
    const float* f2    = (const float*)d_in[2];
    const float* f3    = (const float*)d_in[3];
    const float* boxes = (const float*)d_in[4];
    float*       outp  = (float*)d_out;

    const int R = out_size / (CCH * OUTD * OUTD);   // 512
    dim3 grid(R, 2);
    roi_pool_kernel<<<grid, CCH, 0, stream>>>(f0, f1, f2, f3, boxes, outp);
}

// Round 3
// 371.594 us; speedup vs baseline: 2.6293x; 2.6293x over previous
//
#include <hip/hip_runtime.h>
#include <hip/hip_bf16.h>

// ROIPooler (FPN multi-level ROIAlign, aligned=true), float32 in/out, f32 compute.
// B=2, C=256, N=256 boxes/image -> R=512 ROIs. OUT=7, SR=2 -> 14x14 samples.
// Levels: idx 0..3 <-> feats 256^2/128^2/64^2/32^2, scales 1/4,1/8,1/16,1/32.
//
// R2 structure: (1) NCHW->NHWC transpose of all levels into d_ws (coalesced both
// sides), (2) gather kernel reads channels-last (256B/wave contiguous per
// sample-corner), stages the 50KB output tile in LDS, writes coalesced.

#define OUTD 7
#define SRD  2
#define SD   14     // OUTD*SRD
#define CCH  256
#define NBOX 256
#define BDIM 2

// ---------------- transpose: [B,C,HW] -> [B,HW,C], HW % 64 == 0 ----------------
#define TDIM 64
__global__ __launch_bounds__(256) void transpose_nchw_nhwc(
    const float* __restrict__ in, float* __restrict__ outp, int HW)
{
    __shared__ float tile[TDIM][TDIM + 1];
    const int b  = blockIdx.z;
    const int c0 = blockIdx.y * TDIM;   // channel tile base
    const int p0 = blockIdx.x * TDIM;   // pixel (hw) tile base
    const int tx = threadIdx.x & 63;
    const int ty = threadIdx.x >> 6;    // 0..3

    const float* ip = in + ((size_t)b * CCH + c0) * (size_t)HW + p0;
    #pragma unroll
    for (int k = 0; k < 16; ++k) {
        const int cl = ty + 4 * k;                 // local channel row
        tile[cl][tx] = ip[(size_t)cl * HW + tx];   // coalesced 256B/wave
    }
    __syncthreads();

    float* op = outp + ((size_t)b * HW + p0) * CCH + c0;
    #pragma unroll
    for (int k = 0; k < 16; ++k) {
        const int p = ty + 4 * k;                  // local pixel row
        op[(size_t)p * CCH + tx] = tile[tx][p];    // coalesced 256B/wave
    }
}

// ---------------- gather from NHWC ----------------
__global__ __launch_bounds__(256) void roi_gather_nhwc(
    const float* __restrict__ t0,
    const float* __restrict__ t1,
    const float* __restrict__ t2,
    const float* __restrict__ t3,
    const float* __restrict__ boxes,
    float* __restrict__ out)
{
    const int roi = blockIdx.x;
    const int c   = threadIdx.x;
    const int b   = roi / NBOX;

    const float bx1 = boxes[roi * 4 + 0];
    const float by1 = boxes[roi * 4 + 1];
    const float bx2 = boxes[roi * 4 + 2];
    const float by2 = boxes[roi * 4 + 3];

    // Level assignment (wave-uniform: all threads same roi).
    const float area = (bx2 - bx1) * (by2 - by1);
    const float sz   = sqrtf(area);
    int lvl = (int)floorf(4.0f + log2f(sz * (1.0f / 224.0f) + 1e-8f));
    lvl = min(max(lvl, 2), 5) - 2;   // 0..3

    const int   H     = 256 >> lvl;
    const int   W     = H;
    const float scale = 1.0f / (float)(4 << lvl);

    const float* f = (lvl == 0) ? t0 : (lvl == 1) ? t1 : (lvl == 2) ? t2 : t3;
    const float* fb = f + (size_t)b * H * W * CCH;   // [H,W,C]

    __shared__ int   s_yo0[SD], s_yo1[SD], s_x0[SD], s_x1[SD];  // y offsets pre-multiplied by W
    __shared__ float s_ly[SD], s_lx[SD];
    __shared__ int   s_vy[SD], s_vx[SD];
    __shared__ float s_out[CCH * OUTD * OUTD];   // 50176 B

    if (threadIdx.x < SD) {
        const int i = threadIdx.x;
        const float x1r = bx1 * scale - 0.5f;
        const float y1r = by1 * scale - 0.5f;
        const float x2r = bx2 * scale - 0.5f;
        const float y2r = by2 * scale - 0.5f;
        const float bw = (x2r - x1r) * (1.0f / OUTD);
        const float bh = (y2r - y1r) * (1.0f / OUTD);
        const float g  = ((float)i + 0.5f) * (1.0f / SRD);
        const float ys = y1r + g * bh;
        const float xs = x1r + g * bw;
        s_vy[i] = (ys >= -1.0f) && (ys <= (float)H);
        s_vx[i] = (xs >= -1.0f) && (xs <= (float)W);
        const float yc = fminf(fmaxf(ys, 0.0f), (float)(H - 1));
        const float xc = fminf(fmaxf(xs, 0.0f), (float)(W - 1));
        const int y0 = (int)yc;
        const int x0 = (int)xc;
        s_yo0[i] = y0 * W;
        s_x0[i]  = x0;
        s_yo1[i] = min(y0 + 1, H - 1) * W;
        s_x1[i]  = min(x0 + 1, W - 1);
        s_ly[i]  = yc - (float)y0;
        s_lx[i]  = xc - (float)x0;
    }
    __syncthreads();

    for (int oy = 0; oy < OUTD; ++oy) {
        const int   ia   = oy * 2, ib = oy * 2 + 1;
        const int   vy_a = s_vy[ia], vy_b = s_vy[ib];
        const int   ya0  = s_yo0[ia], ya1 = s_yo1[ia];
        const int   yb0  = s_yo0[ib], yb1 = s_yo1[ib];
        const float lya  = s_ly[ia], hya = 1.0f - lya;
        const float lyb  = s_ly[ib], hyb = 1.0f - lyb;
        #pragma unroll
        for (int ox = 0; ox < OUTD; ++ox) {
            float acc = 0.0f;
            #pragma unroll
            for (int sx = 0; sx < SRD; ++sx) {
                const int j = ox * 2 + sx;
                if (!s_vx[j]) continue;            // wave-uniform
                const int   x0 = s_x0[j], x1 = s_x1[j];
                const float lx = s_lx[j], hx = 1.0f - lx;
                if (vy_a) {
                    const float va = fb[(size_t)(ya0 + x0) * CCH + c];
                    const float vb = fb[(size_t)(ya0 + x1) * CCH + c];
                    const float vc = fb[(size_t)(ya1 + x0) * CCH + c];
                    const float vd = fb[(size_t)(ya1 + x1) * CCH + c];
                    acc += hya * (hx * va + lx * vb) + lya * (hx * vc + lx * vd);
                }
                if (vy_b) {
                    const float va = fb[(size_t)(yb0 + x0) * CCH + c];
                    const float vb = fb[(size_t)(yb0 + x1) * CCH + c];
                    const float vc = fb[(size_t)(yb1 + x0) * CCH + c];
                    const float vd = fb[(size_t)(yb1 + x1) * CCH + c];
                    acc += hyb * (hx * va + lx * vb) + lyb * (hx * vc + lx * vd);
                }
            }
            // stride 49 floats across lanes -> bank = 17*c % 32, conflict-free
            s_out[c * (OUTD * OUTD) + oy * OUTD + ox] = acc * 0.25f;
        }
    }
    __syncthreads();

    float* obase = out + (size_t)roi * CCH * OUTD * OUTD;
    #pragma unroll
    for (int i = 0; i < (CCH * OUTD * OUTD) / CCH; ++i)   // 49 iters
        obase[i * CCH + threadIdx.x] = s_out[i * CCH + threadIdx.x];
}

// ---------------- fallback (R1 kernel): direct NCHW gather ----------------
__global__ __launch_bounds__(256) void roi_pool_kernel(
    const float* __restrict__ f0, const float* __restrict__ f1,
    const float* __restrict__ f2, const float* __restrict__ f3,
    const float* __restrict__ boxes, float* __restrict__ out)
{
    const int roi  = blockIdx.x;
    const int half = blockIdx.y;
    const int c    = threadIdx.x;
    const int b    = roi / NBOX;

    const float bx1 = boxes[roi * 4 + 0];
    const float by1 = boxes[roi * 4 + 1];
    const float bx2 = boxes[roi * 4 + 2];
    const float by2 = boxes[roi * 4 + 3];

    const float area = (bx2 - bx1) * (by2 - by1);
    const float sz   = sqrtf(area);
    int lvl = (int)floorf(4.0f + log2f(sz * (1.0f / 224.0f) + 1e-8f));
    lvl = min(max(lvl, 2), 5) - 2;

    const int   H     = 256 >> lvl;
    const int   W     = H;
    const float scale = 1.0f / (float)(4 << lvl);
    const float* f = (lvl == 0) ? f0 : (lvl == 1) ? f1 : (lvl == 2) ? f2 : f3;

    __shared__ int   s_y0[SD], s_y1[SD], s_x0[SD], s_x1[SD];
    __shared__ float s_ly[SD], s_lx[SD];
    __shared__ int   s_vy[SD], s_vx[SD];

    if (threadIdx.x < SD) {
        const int i = threadIdx.x;
        const float x1r = bx1 * scale - 0.5f;
        const float y1r = by1 * scale - 0.5f;
        const float x2r = bx2 * scale - 0.5f;
        const float y2r = by2 * scale - 0.5f;
        const float bw = (x2r - x1r) * (1.0f / OUTD);
        const float bh = (y2r - y1r) * (1.0f / OUTD);
        const float g  = ((float)i + 0.5f) * (1.0f / SRD);
        const float ys = y1r + g * bh;
        const float xs = x1r + g * bw;
        s_vy[i] = (ys >= -1.0f) && (ys <= (float)H);
        s_vx[i] = (xs >= -1.0f) && (xs <= (float)W);
        const float yc = fminf(fmaxf(ys, 0.0f), (float)(H - 1));
        const float xc = fminf(fmaxf(xs, 0.0f), (float)(W - 1));
        const int y0 = (int)yc;
        const int x0 = (int)xc;
        s_y0[i] = y0; s_x0[i] = x0;
        s_y1[i] = min(y0 + 1, H - 1);
        s_x1[i] = min(x0 + 1, W - 1);
        s_ly[i] = yc - (float)y0;
        s_lx[i] = xc - (float)x0;
    }
    __syncthreads();

    const size_t HW = (size_t)H * (size_t)W;
    const float* fb = f + (size_t)(b * CCH + c) * HW;
    float* orow = out + ((size_t)roi * CCH + c) * (OUTD * OUTD);

    const int oyb = half ? 4 : 0;
    const int oye = half ? 7 : 4;
    for (int oy = oyb; oy < oye; ++oy) {
        const int   ia   = oy * 2, ib = oy * 2 + 1;
        const int   vy_a = s_vy[ia], vy_b = s_vy[ib];
        const int   ya0  = s_y0[ia] * W, ya1 = s_y1[ia] * W;
        const int   yb0  = s_y0[ib] * W, yb1 = s_y1[ib] * W;
        const float lya  = s_ly[ia], hya = 1.0f - lya;
        const float lyb  = s_ly[ib], hyb = 1.0f - lyb;
        #pragma unroll
        for (int ox = 0; ox < OUTD; ++ox) {
            float acc = 0.0f;
            #pragma unroll
            for (int sx = 0; sx < SRD; ++sx) {
                const int j = ox * 2 + sx;
                if (!s_vx[j]) continue;
                const int   x0 = s_x0[j], x1 = s_x1[j];
                const float lx = s_lx[j], hx = 1.0f - lx;
                if (vy_a) acc += hya * (hx * fb[ya0 + x0] + lx * fb[ya0 + x1])
                               + lya * (hx * fb[ya1 + x0] + lx * fb[ya1 + x1]);
                if (vy_b) acc += hyb * (hx * fb[yb0 + x0] + lx * fb[yb0 + x1])
                               + lyb * (hx * fb[yb1 + x0] + lx * fb[yb1 + x1]);
            }
            orow[oy * OUTD + ox] = acc * 0.25f;
        }
    }
}

extern "C" void kernel_launch(void* const* d_in, const int* in_sizes, int n_in,
                              void* d_out, int out_size, void* d_ws, size_t ws_size,
                              hipStream_t stream) {
    const float* f0    = (const float*)d_in[0];
    const float* f1    = (const float*)d_in[1];
    const float* f2    = (const float*)d_in[2];
    const float* f3    = (const float*)d_in[3];
    const float* boxes = (const float*)d_in[4];
    float*       outp  = (float*)d_out;

    const int R = out_size / (CCH * OUTD * OUTD);   // 512

    // Workspace layout (floats): t0 | t1 | t2 | t3, NHWC per level.
    const size_t n0 = (size_t)BDIM * CCH * 256 * 256;
    const size_t n1 = (size_t)BDIM * CCH * 128 * 128;
    const size_t n2 = (size_t)BDIM * CCH * 64 * 64;
    const size_t n3 = (size_t)BDIM * CCH * 32 * 32;
    const size_t need = (n0 + n1 + n2 + n3) * sizeof(float);

    if (ws_size >= need) {
        float* t0 = (float*)d_ws;
        float* t1 = t0 + n0;
        float* t2 = t1 + n1;
        float* t3 = t2 + n2;

        transpose_nchw_nhwc<<<dim3(256 * 256 / TDIM, CCH / TDIM, BDIM), 256, 0, stream>>>(f0, t0, 256 * 256);
        transpose_nchw_nhwc<<<dim3(128 * 128 / TDIM, CCH / TDIM, BDIM), 256, 0, stream>>>(f1, t1, 128 * 128);
        transpose_nchw_nhwc<<<dim3( 64 *  64 / TDIM, CCH / TDIM, BDIM), 256, 0, stream>>>(f2, t2,  64 *  64);
        transpose_nchw_nhwc<<<dim3( 32 *  32 / TDIM, CCH / TDIM, BDIM), 256, 0, stream>>>(f3, t3,  32 *  32);

        roi_gather_nhwc<<<dim3(R), CCH, 0, stream>>>(t0, t1, t2, t3, boxes, outp);
    } else {
        // Fallback: direct NCHW gather (correct, slower).
        roi_pool_kernel<<<dim3(R, 2), CCH, 0, stream>>>(f0, f1, f2, f3, boxes, outp);
    }
}

// Round 4
// 319.714 us; speedup vs baseline: 3.0560x; 1.1623x over previous
//
#include <hip/hip_runtime.h>

// ROIPooler (FPN multi-level ROIAlign, aligned=true), float32 in/out.
// R3: (1) single fused float4 NCHW->NHWC transpose of all 4 levels,
//     (2) branchless gather (masks folded into weights) for deep MLP.

#define OUTD 7
#define SRD  2
#define SD   14
#define CCH  256
#define NBOX 256
#define BDIM 2

// ---------------- fused transpose: [B,C,HW] -> [B,HW,C] for all levels ----------------
// 64ch x 64px tiles. L0 HW=65536 (1024 ptiles), L1 16384 (256), L2 4096 (64), L3 1024 (16).
#define PT0 1024
#define PT1 256
#define PT2 64
#define PT3 16
#define CT  4
#define NB0 (PT0*CT*BDIM)   // 8192
#define NB1 (PT1*CT*BDIM)   // 2048
#define NB2 (PT2*CT*BDIM)   // 512
#define NB3 (PT3*CT*BDIM)   // 128

__global__ __launch_bounds__(256) void transpose_all(
    const float* __restrict__ f0, const float* __restrict__ f1,
    const float* __restrict__ f2, const float* __restrict__ f3,
    float* __restrict__ t0, float* __restrict__ t1,
    float* __restrict__ t2, float* __restrict__ t3)
{
    const int bid = blockIdx.x;
    const float* in; float* outp; int HW, PT, rel;
    if (bid < NB0)                  { in = f0; outp = t0; HW = 65536; PT = PT0; rel = bid; }
    else if (bid < NB0 + NB1)       { in = f1; outp = t1; HW = 16384; PT = PT1; rel = bid - NB0; }
    else if (bid < NB0 + NB1 + NB2) { in = f2; outp = t2; HW = 4096;  PT = PT2; rel = bid - NB0 - NB1; }
    else                            { in = f3; outp = t3; HW = 1024;  PT = PT3; rel = bid - NB0 - NB1 - NB2; }

    const int ptile = rel & (PT - 1);
    const int rest  = rel / PT;
    const int ctile = rest & (CT - 1);
    const int b     = rest / CT;
    const int p0 = ptile * 64, c0 = ctile * 64;

    __shared__ float s[64][65];   // [pixel][channel], +1 pad
    const int t  = threadIdx.x;
    const int pj = (t & 15) * 4;  // pixel offset for load phase
    const int cw = t >> 4;        // channel row for load phase

    const float* ip = in + ((size_t)b * CCH + c0) * (size_t)HW + p0;
    #pragma unroll
    for (int r = 0; r < 4; ++r) {
        const int cl = cw + 16 * r;
        const float4 v = *(const float4*)(ip + (size_t)cl * HW + pj);  // 1KB/wave coalesced
        s[pj + 0][cl] = v.x; s[pj + 1][cl] = v.y;
        s[pj + 2][cl] = v.z; s[pj + 3][cl] = v.w;   // <=2-way banks: free
    }
    __syncthreads();

    const int cj = (t & 15) * 4;  // channel offset for store phase
    const int pw = t >> 4;        // pixel row for store phase
    float* op = outp + ((size_t)b * HW + p0) * CCH + c0;
    #pragma unroll
    for (int r = 0; r < 4; ++r) {
        const int pl = pw + 16 * r;
        const float4 v = make_float4(s[pl][cj + 0], s[pl][cj + 1],
                                     s[pl][cj + 2], s[pl][cj + 3]);
        *(float4*)(op + (size_t)pl * CCH + cj) = v;   // 1KB/wave coalesced
    }
}

// ---------------- branchless gather from NHWC ----------------
__global__ __launch_bounds__(256) void roi_gather_nhwc(
    const float* __restrict__ t0, const float* __restrict__ t1,
    const float* __restrict__ t2, const float* __restrict__ t3,
    const float* __restrict__ boxes, float* __restrict__ out)
{
    const int roi = blockIdx.x;
    const int c   = threadIdx.x;
    const int b   = roi / NBOX;

    const float bx1 = boxes[roi * 4 + 0];
    const float by1 = boxes[roi * 4 + 1];
    const float bx2 = boxes[roi * 4 + 2];
    const float by2 = boxes[roi * 4 + 3];

    // Level assignment (wave-uniform).
    const float area = (bx2 - bx1) * (by2 - by1);
    const float sz   = sqrtf(area);
    int lvl = (int)floorf(4.0f + log2f(sz * (1.0f / 224.0f) + 1e-8f));
    lvl = min(max(lvl, 2), 5) - 2;

    const int   H     = 256 >> lvl;
    const int   W     = H;
    const float scale = 1.0f / (float)(4 << lvl);

    const float* f  = (lvl == 0) ? t0 : (lvl == 1) ? t1 : (lvl == 2) ? t2 : t3;
    const float* fb = f + (size_t)b * H * W * CCH;   // [H,W,C]

    // Per-ROI metadata: offsets pre-scaled, validity folded into weights.
    __shared__ int   s_yo0[SD], s_yo1[SD], s_xo0[SD], s_xo1[SD];
    __shared__ float s_wyh[SD], s_wyl[SD], s_wxh[SD], s_wxl[SD];
    __shared__ float s_out[CCH * OUTD * OUTD];   // 50176 B

    if (threadIdx.x < SD) {
        const int i = threadIdx.x;
        const float x1r = bx1 * scale - 0.5f;
        const float y1r = by1 * scale - 0.5f;
        const float x2r = bx2 * scale - 0.5f;
        const float y2r = by2 * scale - 0.5f;
        const float bw = (x2r - x1r) * (1.0f / OUTD);
        const float bh = (y2r - y1r) * (1.0f / OUTD);
        const float g  = ((float)i + 0.5f) * (1.0f / SRD);
        const float ys = y1r + g * bh;
        const float xs = x1r + g * bw;
        const float vy = ((ys >= -1.0f) && (ys <= (float)H)) ? 1.0f : 0.0f;
        const float vx = ((xs >= -1.0f) && (xs <= (float)W)) ? 1.0f : 0.0f;
        const float yc = fminf(fmaxf(ys, 0.0f), (float)(H - 1));
        const float xc = fminf(fmaxf(xs, 0.0f), (float)(W - 1));
        const int y0 = (int)yc;
        const int x0 = (int)xc;
        const float ly = yc - (float)y0;
        const float lx = xc - (float)x0;
        s_yo0[i] = y0 * W * CCH;
        s_yo1[i] = min(y0 + 1, H - 1) * W * CCH;
        s_xo0[i] = x0 * CCH;
        s_xo1[i] = min(x0 + 1, W - 1) * CCH;
        s_wyh[i] = vy * (1.0f - ly);
        s_wyl[i] = vy * ly;
        s_wxh[i] = vx * (1.0f - lx);
        s_wxl[i] = vx * lx;
    }
    __syncthreads();

    // X metadata into registers (broadcast LDS reads, then fully unrolled use).
    int   xo0[SD], xo1[SD];
    float wxh[SD], wxl[SD];
    #pragma unroll
    for (int j = 0; j < SD; ++j) {
        xo0[j] = s_xo0[j]; xo1[j] = s_xo1[j];
        wxh[j] = s_wxh[j]; wxl[j] = s_wxl[j];
    }

    const float* fc = fb + c;
    for (int oy = 0; oy < OUTD; ++oy) {
        const int ia = 2 * oy, ib = ia + 1;
        const float* ra0 = fc + s_yo0[ia];
        const float* ra1 = fc + s_yo1[ia];
        const float* rb0 = fc + s_yo0[ib];
        const float* rb1 = fc + s_yo1[ib];
        const float wah = s_wyh[ia], wal = s_wyl[ia];
        const float wbh = s_wyh[ib], wbl = s_wyl[ib];
        #pragma unroll
        for (int ox = 0; ox < OUTD; ++ox) {
            float acc = 0.0f;
            #pragma unroll
            for (int sx = 0; sx < SRD; ++sx) {
                const int j = 2 * ox + sx;
                const float h = wxh[j], l = wxl[j];
                const int o0 = xo0[j], o1 = xo1[j];
                acc += wah * (h * ra0[o0] + l * ra0[o1])
                     + wal * (h * ra1[o0] + l * ra1[o1])
                     + wbh * (h * rb0[o0] + l * rb0[o1])
                     + wbl * (h * rb1[o0] + l * rb1[o1]);
            }
            // stride 49 floats: bank = 17*c % 32 -> 2-way max, free
            s_out[c * (OUTD * OUTD) + oy * OUTD + ox] = acc * 0.25f;
        }
    }
    __syncthreads();

    float* ob = out + (size_t)roi * CCH * OUTD * OUTD;
    #pragma unroll
    for (int i = 0; i < OUTD * OUTD; ++i)   // 49 coalesced 1KB stores
        ob[i * CCH + threadIdx.x] = s_out[i * CCH + threadIdx.x];
}

// ---------------- fallback: direct NCHW gather (if ws too small) ----------------
__global__ __launch_bounds__(256) void roi_pool_kernel(
    const float* __restrict__ f0, const float* __restrict__ f1,
    const float* __restrict__ f2, const float* __restrict__ f3,
    const float* __restrict__ boxes, float* __restrict__ out)
{
    const int roi  = blockIdx.x;
    const int half = blockIdx.y;
    const int c    = threadIdx.x;
    const int b    = roi / NBOX;

    const float bx1 = boxes[roi * 4 + 0];
    const float by1 = boxes[roi * 4 + 1];
    const float bx2 = boxes[roi * 4 + 2];
    const float by2 = boxes[roi * 4 + 3];

    const float area = (bx2 - bx1) * (by2 - by1);
    const float sz   = sqrtf(area);
    int lvl = (int)floorf(4.0f + log2f(sz * (1.0f / 224.0f) + 1e-8f));
    lvl = min(max(lvl, 2), 5) - 2;

    const int   H     = 256 >> lvl;
    const int   W     = H;
    const float scale = 1.0f / (float)(4 << lvl);
    const float* f = (lvl == 0) ? f0 : (lvl == 1) ? f1 : (lvl == 2) ? f2 : f3;

    __shared__ int   s_y0[SD], s_y1[SD], s_x0[SD], s_x1[SD];
    __shared__ float s_ly[SD], s_lx[SD];
    __shared__ int   s_vy[SD], s_vx[SD];

    if (threadIdx.x < SD) {
        const int i = threadIdx.x;
        const float x1r = bx1 * scale - 0.5f;
        const float y1r = by1 * scale - 0.5f;
        const float x2r = bx2 * scale - 0.5f;
        const float y2r = by2 * scale - 0.5f;
        const float bw = (x2r - x1r) * (1.0f / OUTD);
        const float bh = (y2r - y1r) * (1.0f / OUTD);
        const float g  = ((float)i + 0.5f) * (1.0f / SRD);
        const float ys = y1r + g * bh;
        const float xs = x1r + g * bw;
        s_vy[i] = (ys >= -1.0f) && (ys <= (float)H);
        s_vx[i] = (xs >= -1.0f) && (xs <= (float)W);
        const float yc = fminf(fmaxf(ys, 0.0f), (float)(H - 1));
        const float xc = fminf(fmaxf(xs, 0.0f), (float)(W - 1));
        const int y0 = (int)yc;
        const int x0 = (int)xc;
        s_y0[i] = y0; s_x0[i] = x0;
        s_y1[i] = min(y0 + 1, H - 1);
        s_x1[i] = min(x0 + 1, W - 1);
        s_ly[i] = yc - (float)y0;
        s_lx[i] = xc - (float)x0;
    }
    __syncthreads();

    const size_t HW = (size_t)H * (size_t)W;
    const float* fb = f + (size_t)(b * CCH + c) * HW;
    float* orow = out + ((size_t)roi * CCH + c) * (OUTD * OUTD);

    const int oyb = half ? 4 : 0;
    const int oye = half ? 7 : 4;
    for (int oy = oyb; oy < oye; ++oy) {
        const int   ia   = oy * 2, ib = oy * 2 + 1;
        const int   vy_a = s_vy[ia], vy_b = s_vy[ib];
        const int   ya0  = s_y0[ia] * W, ya1 = s_y1[ia] * W;
        const int   yb0  = s_y0[ib] * W, yb1 = s_y1[ib] * W;
        const float lya  = s_ly[ia], hya = 1.0f - lya;
        const float lyb  = s_ly[ib], hyb = 1.0f - lyb;
        #pragma unroll
        for (int ox = 0; ox < OUTD; ++ox) {
            float acc = 0.0f;
            #pragma unroll
            for (int sx = 0; sx < SRD; ++sx) {
                const int j = ox * 2 + sx;
                if (!s_vx[j]) continue;
                const int   x0 = s_x0[j], x1 = s_x1[j];
                const float lx = s_lx[j], hx = 1.0f - lx;
                if (vy_a) acc += hya * (hx * fb[ya0 + x0] + lx * fb[ya0 + x1])
                               + lya * (hx * fb[ya1 + x0] + lx * fb[ya1 + x1]);
                if (vy_b) acc += hyb * (hx * fb[yb0 + x0] + lx * fb[yb0 + x1])
                               + lyb * (hx * fb[yb1 + x0] + lx * fb[yb1 + x1]);
            }
            orow[oy * OUTD + ox] = acc * 0.25f;
        }
    }
}

extern "C" void kernel_launch(void* const* d_in, const int* in_sizes, int n_in,
                              void* d_out, int out_size, void* d_ws, size_t ws_size,
                              hipStream_t stream) {
    const float* f0    = (const float*)d_in[0];
    const float* f1    = (const float*)d_in[1];
    const float* f2    = (const float*)d_in[2];
    const float* f3    = (const float*)d_in[3];
    const float* boxes = (const float*)d_in[4];
    float*       outp  = (float*)d_out;

    const int R = out_size / (CCH * OUTD * OUTD);   // 512

    const size_t n0 = (size_t)BDIM * CCH * 256 * 256;
    const size_t n1 = (size_t)BDIM * CCH * 128 * 128;
    const size_t n2 = (size_t)BDIM * CCH * 64 * 64;
    const size_t n3 = (size_t)BDIM * CCH * 32 * 32;
    const size_t need = (n0 + n1 + n2 + n3) * sizeof(float);

    if (ws_size >= need) {
        float* t0 = (float*)d_ws;
        float* t1 = t0 + n0;
        float* t2 = t1 + n1;
        float* t3 = t2 + n2;

        transpose_all<<<NB0 + NB1 + NB2 + NB3, 256, 0, stream>>>(
            f0, f1, f2, f3, t0, t1, t2, t3);
        roi_gather_nhwc<<<R, CCH, 0, stream>>>(t0, t1, t2, t3, boxes, outp);
    } else {
        roi_pool_kernel<<<dim3(R, 2), CCH, 0, stream>>>(f0, f1, f2, f3, boxes, outp);
    }
}